// Round 18
// baseline (123.138 us; speedup 1.0000x reference)
//
#include <hip/hip_runtime.h>
#include <hip/hip_bf16.h>
#include <cstddef>

#define BN 4096
#define DD 128
#define NSTEPS 100
#define PTILE 128
#define PLSTR 136   // bf16 elems per LDS row: 128 + 8 pad -> 272 B stride
#define GRID_T (BN / PTILE)   // 32
#define NOFF 496    // strictly-upper tile pairs (ti<tj)
#define NBLK 528    // + 32 diagonal tiles
#define NREPC 16    // cdf replicas, stride 101 (101%32=5 -> spread banks)

typedef __attribute__((ext_vector_type(8))) short bf16x8;
typedef __attribute__((ext_vector_type(4))) float f32x4;

__device__ __forceinline__ void faddf(float* p, float v) { unsafeAtomicAdd(p, v); }

// ---------------- normalize + convert to bf16: one wave per row ----------------
__global__ __launch_bounds__(256) void hl_normalize(const float* __restrict__ emb,
                                                    ushort* __restrict__ out) {
    int w = threadIdx.x >> 6;
    int lane = threadIdx.x & 63;
    int row = (blockIdx.x << 2) + w;
    const float2 v = *(const float2*)(emb + (size_t)row * DD + 2 * lane);
    float ss = v.x * v.x + v.y * v.y;
    #pragma unroll
    for (int off = 32; off > 0; off >>= 1) ss += __shfl_xor(ss, off);
    float inv = 1.0f / sqrtf(ss);
    __hip_bfloat16 b0 = __float2bfloat16(v.x * inv);
    __hip_bfloat16 b1 = __float2bfloat16(v.y * inv);
    ushort2 pk;
    pk.x = *(ushort*)&b0;
    pk.y = *(ushort*)&b1;
    *(ushort2*)(out + (size_t)row * DD + 2 * lane) = pk;
}

// ---------------- POS histogram: per-class pair enumeration ----------------
// Same-class pairs only (~82K of 8.4M). 200 one-wave blocks: class = bid>>1,
// a-parity = bid&1. Per-lane f32 LDS columns [100][64]: bank = lane%32, no
// races, no atomics in the hot loop.
__global__ __launch_bounds__(64) void hl_poscls(const ushort* __restrict__ nemb,
                                                const int* __restrict__ cls,
                                                float* __restrict__ gPos) {
    const int c = blockIdx.x >> 1;
    const int par = blockIdx.x & 1;
    __shared__ int mcnt;
    __shared__ int idx[256];
    __shared__ float col[NSTEPS][64];   // 25.6 KB
    const int lane = threadIdx.x;
    if (lane == 0) mcnt = 0;
    #pragma unroll 4
    for (int b = 0; b < NSTEPS; ++b) col[b][lane] = 0.f;
    __syncthreads();
    for (int i = lane; i < BN; i += 64)
        if (cls[i] == c) { int p = atomicAdd(&mcnt, 1); if (p < 256) idx[p] = i; }
    __syncthreads();
    const int m = mcnt > 256 ? 256 : mcnt;

    constexpr float STEPF = 2.0f / 99.0f;
    constexpr float INVSTEP = 49.5f;
    constexpr float CLIPV = 1.0f - 1e-6f;

    for (int a = par; a < m - 1; a += 2) {
        const ushort* ra = nemb + (size_t)idx[a] * DD;
        for (int b = a + 1 + lane; b < m; b += 64) {
            const ushort* rb = nemb + (size_t)idx[b] * DD;
            float s0 = 0.f, s1 = 0.f;
            #pragma unroll
            for (int k = 0; k < DD; k += 8) {
                bf16x8 va = *(const bf16x8*)(ra + k);
                bf16x8 vb = *(const bf16x8*)(rb + k);
                #pragma unroll
                for (int e = 0; e < 8; e += 2) {
                    float a0 = __uint_as_float((unsigned)(ushort)va[e] << 16);
                    float b0 = __uint_as_float((unsigned)(ushort)vb[e] << 16);
                    float a1 = __uint_as_float((unsigned)(ushort)va[e + 1] << 16);
                    float b1 = __uint_as_float((unsigned)(ushort)vb[e + 1] << 16);
                    s0 = fmaf(a0, b0, s0);
                    s1 = fmaf(a1, b1, s1);
                }
            }
            float s = s0 + s1;
            s = fminf(fmaxf(s, -CLIPV), CLIPV);
            float u = (s + CLIPV) * INVSTEP;
            int jb = (int)u;
            if (jb > 98) jb = 98;
            float t_j = (float)jb * STEPF - 1.0f;
            float w_hi = (s - t_j) * INVSTEP;
            float w_lo = 1.0f - w_hi;
            col[jb][lane] += w_lo;        // per-lane column: no race
            col[jb + 1][lane] += w_hi;
        }
    }
    __syncthreads();
    for (int b = 0; b < NSTEPS; ++b) {
        float v = col[b][lane];
        #pragma unroll
        for (int off = 32; off > 0; off >>= 1) v += __shfl_xor(v, off);
        if (lane == 0 && v != 0.f) faddf(&gPos[b], v);
    }
}

// ---------------- NEG pass: MFMA GEMM + read-only cdf gather ----------------
// Per pair: 2 LDS gathers + 2 FMA into a register. No RMW histogram at all.
// Last-finished block (device-scope ticket) writes out[0].
__global__ __launch_bounds__(256, 2) void hl_neg(const ushort* __restrict__ nemb,
                                                 const int* __restrict__ cls,
                                                 const float* __restrict__ gPos,
                                                 float* __restrict__ gLoss,
                                                 float* __restrict__ gCnt,
                                                 unsigned int* __restrict__ gDone,
                                                 float* __restrict__ out) {
    // flat grid: blocks 0..495 = strictly-upper tile pairs, 496..527 = diagonal
    int ti, tj;
    {
        int t = blockIdx.x;
        if (t < NOFF) {
            ti = 0;
            int rem = t;
            while (rem >= GRID_T - 1 - ti) { rem -= GRID_T - 1 - ti; ++ti; }
            tj = ti + 1 + rem;
        } else {
            ti = tj = t - NOFF;
        }
    }

    __shared__ ushort As[PTILE * PLSTR];      // 34816 B
    __shared__ ushort Bs[PTILE * PLSTR];      // 34816 B
    __shared__ float cdfL[NREPC * 101];       // 6464 B
    __shared__ float scan[128];
    __shared__ float red[9];                  // 4 loss + 4 cnt + sp
    __shared__ int clsA[PTILE], clsB[PTILE];

    const int tid = threadIdx.x;
    if (tid < PTILE) clsA[tid] = cls[ti * PTILE + tid];
    else             clsB[tid - PTILE] = cls[tj * PTILE + (tid - PTILE)];

    // ---- cdf prologue: inclusive scan of gPos, 16 LDS replicas ----
    if (tid < 128) scan[tid] = (tid < NSTEPS) ? gPos[tid] : 0.f;
    __syncthreads();
    for (int off = 1; off < 128; off <<= 1) {
        float v = 0.f;
        if (tid < 128 && tid >= off) v = scan[tid - off];
        __syncthreads();
        if (tid < 128) scan[tid] += v;
        __syncthreads();
    }
    if (tid == 0) red[8] = scan[NSTEPS - 1];   // sp
    __syncthreads();
    const float invsp = 1.0f / red[8];
    for (int i = tid; i < NREPC * NSTEPS; i += 256) {
        int r = i / NSTEPS, b = i - r * NSTEPS;
        cdfL[r * 101 + b] = scan[b] * invsp;
    }

    // ---- stage tiles ----
    #pragma unroll
    for (int it = 0; it < 8; ++it) {
        int idx = it * 256 + tid;
        int row = idx >> 4;
        int cch = idx & 15;
        const float4 va = *(const float4*)(nemb + (size_t)(ti * PTILE + row) * DD + cch * 8);
        const float4 vb = *(const float4*)(nemb + (size_t)(tj * PTILE + row) * DD + cch * 8);
        *(float4*)(&As[row * PLSTR + cch * 8]) = va;
        *(float4*)(&Bs[row * PLSTR + cch * 8]) = vb;
    }
    __syncthreads();   // covers cdf replicas + cls + tiles

    const int lane = tid & 63;
    const int wid = tid >> 6;
    const int wr = wid >> 1, wc = wid & 1;
    const int lr = lane & 15;
    const int kg = lane >> 4;

    f32x4 zero4 = {0.f, 0.f, 0.f, 0.f};
    f32x4 acc[4][4];
    #pragma unroll
    for (int a = 0; a < 4; ++a)
        #pragma unroll
        for (int b = 0; b < 4; ++b) acc[a][b] = zero4;

    #pragma unroll
    for (int ks = 0; ks < 4; ++ks) {
        bf16x8 af[4], bfr[4];
        #pragma unroll
        for (int f = 0; f < 4; ++f) {
            int arow = wr * 64 + f * 16 + lr;
            af[f] = *(const bf16x8*)(&As[arow * PLSTR + ks * 32 + kg * 8]);
            int brow = wc * 64 + f * 16 + lr;
            bfr[f] = *(const bf16x8*)(&Bs[brow * PLSTR + ks * 32 + kg * 8]);
        }
        #pragma unroll
        for (int fa = 0; fa < 4; ++fa)
            #pragma unroll
            for (int fb = 0; fb < 4; ++fb)
                acc[fa][fb] = __builtin_amdgcn_mfma_f32_16x16x32_bf16(af[fa], bfr[fb], acc[fa][fb], 0, 0, 0);
    }

    // ---- gather epilogue: branch-free, read-only cdf lookups ----
    constexpr float STEPF = 2.0f / 99.0f;
    constexpr float INVSTEP = 49.5f;
    constexpr float CLIPV = 1.0f - 1e-6f;

    const int li_base = wr * 64 + (kg << 2);
    const int lj_base = wc * 64 + lr;
    const float* crep = &cdfL[(lane & 15) * 101];

    int ca[16];
    #pragma unroll
    for (int fa = 0; fa < 4; ++fa)
        #pragma unroll
        for (int j = 0; j < 4; ++j) ca[fa * 4 + j] = clsA[li_base + fa * 16 + j];

    const bool offdiag = (ti != tj);
    float lacc = 0.f, lcnt = 0.f;

    #pragma unroll
    for (int fb = 0; fb < 4; ++fb) {
        const int lj = lj_base + fb * 16;
        const int cb = clsB[lj];
        #pragma unroll
        for (int fa = 0; fa < 4; ++fa) {
            const int li0 = li_base + fa * 16;
            f32x4 v = acc[fa][fb];
            #pragma unroll
            for (int j = 0; j < 4; ++j) {
                const int li = li0 + j;
                const bool mneg = (offdiag || (li < lj)) && (ca[fa * 4 + j] != cb);
                float s = v[j];
                s = fminf(fmaxf(s, -CLIPV), CLIPV);
                float u = (s + CLIPV) * INVSTEP;
                int jb = (int)u;
                if (jb > 98) jb = 98;
                float t_j = (float)jb * STEPF - 1.0f;
                float w_hi = (s - t_j) * INVSTEP;
                float w_lo = 1.0f - w_hi;
                float c0 = crep[jb];
                float c1 = crep[jb + 1];
                float m = mneg ? 1.0f : 0.0f;
                lacc = fmaf(m, fmaf(w_lo, c0, w_hi * c1), lacc);
                lcnt += m;
            }
        }
    }

    // ---- reduce: wave shuffle -> 4 partials -> 2 atomics into 32 slots ----
    #pragma unroll
    for (int off = 32; off > 0; off >>= 1) {
        lacc += __shfl_xor(lacc, off);
        lcnt += __shfl_xor(lcnt, off);
    }
    if (lane == 0) { red[wid] = lacc; red[4 + wid] = lcnt; }
    __syncthreads();
    if (tid == 0) {
        float L = red[0] + red[1] + red[2] + red[3];
        float C = red[4] + red[5] + red[6] + red[7];
        faddf(&gLoss[blockIdx.x & 31], L);
        faddf(&gCnt[blockIdx.x & 31], C);
        __threadfence();
        unsigned int tk = atomicAdd(gDone, 1u);
        if (tk == NBLK - 1) {          // last block finalizes
            __threadfence();
            float ls = 0.f, cs = 0.f;
            for (int i = 0; i < 32; ++i) {
                ls += __hip_atomic_load(&gLoss[i], __ATOMIC_RELAXED, __HIP_MEMORY_SCOPE_AGENT);
                cs += __hip_atomic_load(&gCnt[i], __ATOMIC_RELAXED, __HIP_MEMORY_SCOPE_AGENT);
            }
            // cdf is already normalized by 1/sp, so loss = ls / sn only.
            // (r17 bug: divided by sp twice -> out ~ 0.)
            out[0] = ls / cs;
        }
    }
}

extern "C" void kernel_launch(void* const* d_in, const int* in_sizes, int n_in,
                              void* d_out, int out_size, void* d_ws, size_t ws_size,
                              hipStream_t stream) {
    const float* emb = (const float*)d_in[0];
    const int* classes = (const int*)d_in[1];
    float* out = (float*)d_out;

    ushort* nemb = (ushort*)d_ws;                                   // 1 MB
    float* gPos = (float*)((char*)d_ws + (size_t)BN * DD * sizeof(ushort));
    float* gLoss = gPos + NSTEPS;           // 32 slots
    float* gCnt = gLoss + 32;               // 32 slots
    unsigned int* gDone = (unsigned int*)(gCnt + 32);

    hipMemsetAsync(gPos, 0, (NSTEPS + 64 + 1) * sizeof(float), stream);

    hl_normalize<<<BN / 4, 256, 0, stream>>>(emb, nemb);
    hl_poscls<<<200, 64, 0, stream>>>(nemb, classes, gPos);
    hl_neg<<<NBLK, 256, 0, stream>>>(nemb, classes, gPos, gLoss, gCnt, gDone, out);
}

// Round 20
// 76.809 us; speedup vs baseline: 1.6032x; 1.6032x over previous
//
#include <hip/hip_runtime.h>
#include <hip/hip_bf16.h>
#include <cstddef>

#define BN 4096
#define DD 128
#define NSTEPS 100
#define PTILE 128
#define PLSTR 136   // bf16 elems per LDS row: 128 + 8 pad -> 272 B stride
#define GRID_T (BN / PTILE)   // 32
#define NOFF 496    // strictly-upper tile pairs (ti<tj)
#define NBLK 528    // + 32 diagonal tiles
#define NREPC 16    // cdf replicas, stride 101 (101%32=5 -> spread banks)

typedef __attribute__((ext_vector_type(8))) short bf16x8;
typedef __attribute__((ext_vector_type(4))) float f32x4;

__device__ __forceinline__ void faddf(float* p, float v) { unsafeAtomicAdd(p, v); }

// ---------------- normalize + convert to bf16: one wave per row ----------------
__global__ __launch_bounds__(256) void hl_normalize(const float* __restrict__ emb,
                                                    ushort* __restrict__ out) {
    int w = threadIdx.x >> 6;
    int lane = threadIdx.x & 63;
    int row = (blockIdx.x << 2) + w;
    const float2 v = *(const float2*)(emb + (size_t)row * DD + 2 * lane);
    float ss = v.x * v.x + v.y * v.y;
    #pragma unroll
    for (int off = 32; off > 0; off >>= 1) ss += __shfl_xor(ss, off);
    float inv = 1.0f / sqrtf(ss);
    __hip_bfloat16 b0 = __float2bfloat16(v.x * inv);
    __hip_bfloat16 b1 = __float2bfloat16(v.y * inv);
    ushort2 pk;
    pk.x = *(ushort*)&b0;
    pk.y = *(ushort*)&b1;
    *(ushort2*)(out + (size_t)row * DD + 2 * lane) = pk;
}

// ---------------- POS histogram: per-class, 256-thread flattened pairs ----------
// r18 post-mortem: 64-thread serial version was latency-bound (95us, 1.8% occ).
// Now: deterministic scan-compaction of class members, then flat m*m pair loop
// across 256 threads (~3-7 pairs each, independent -> MLP), 16-replica LDS
// atomic hist (~1.6K lane-ops/block ~ 4us at measured 6.3cyc/op).
__global__ __launch_bounds__(256) void hl_poscls(const ushort* __restrict__ nemb,
                                                 const int* __restrict__ cls,
                                                 float* __restrict__ gPos) {
    const int c = blockIdx.x;           // one block per class
    __shared__ int idx[256];
    __shared__ int scan[256];
    __shared__ float hpos[NREPC * 101]; // 6464 B
    __shared__ int mTot;
    const int tid = threadIdx.x;

    for (int i = tid; i < NREPC * 101; i += 256) hpos[i] = 0.f;

    // deterministic compaction: thread t owns elements [16t, 16t+16)
    const int base = tid * 16;
    int myCnt = 0;
    #pragma unroll
    for (int k = 0; k < 16; ++k) myCnt += (cls[base + k] == c);
    scan[tid] = myCnt;
    __syncthreads();
    for (int s = 1; s < 256; s <<= 1) {
        int v = (tid >= s) ? scan[tid - s] : 0;
        __syncthreads();
        scan[tid] += v;
        __syncthreads();
    }
    int w = scan[tid] - myCnt;          // exclusive offset
    if (tid == 255) mTot = scan[255] > 256 ? 256 : scan[255];
    #pragma unroll
    for (int k = 0; k < 16; ++k) {
        if (cls[base + k] == c && w < 256) { idx[w] = base + k; ++w; }
    }
    __syncthreads();
    const int m = mTot;

    constexpr float STEPF = 2.0f / 99.0f;
    constexpr float INVSTEP = 49.5f;
    constexpr float CLIPV = 1.0f - 1e-6f;
    const int rep = (tid & 15) * 101;

    const int P2 = m * m;
    for (int p = tid; p < P2; p += 256) {
        int a = p / m, b = p - a * m;
        if (a >= b) continue;           // strict upper triangle
        const ushort* ra = nemb + (size_t)idx[a] * DD;
        const ushort* rb = nemb + (size_t)idx[b] * DD;
        float s0 = 0.f, s1 = 0.f;
        #pragma unroll
        for (int k = 0; k < DD; k += 8) {
            bf16x8 va = *(const bf16x8*)(ra + k);
            bf16x8 vb = *(const bf16x8*)(rb + k);
            #pragma unroll
            for (int e = 0; e < 8; e += 2) {
                float a0 = __uint_as_float((unsigned)(ushort)va[e] << 16);
                float b0 = __uint_as_float((unsigned)(ushort)vb[e] << 16);
                float a1 = __uint_as_float((unsigned)(ushort)va[e + 1] << 16);
                float b1 = __uint_as_float((unsigned)(ushort)vb[e + 1] << 16);
                s0 = fmaf(a0, b0, s0);
                s1 = fmaf(a1, b1, s1);
            }
        }
        float s = s0 + s1;
        s = fminf(fmaxf(s, -CLIPV), CLIPV);
        float u = (s + CLIPV) * INVSTEP;
        int jb = (int)u;
        if (jb > 98) jb = 98;
        float t_j = (float)jb * STEPF - 1.0f;
        float w_hi = (s - t_j) * INVSTEP;
        float w_lo = 1.0f - w_hi;
        faddf(&hpos[rep + jb], w_lo);
        faddf(&hpos[rep + jb + 1], w_hi);
    }
    __syncthreads();
    if (tid < NSTEPS) {
        float v = 0.f;
        #pragma unroll
        for (int r = 0; r < NREPC; ++r) v += hpos[r * 101 + tid];
        if (v != 0.f) faddf(&gPos[tid], v);
    }
}

// ---------------- NEG pass: MFMA GEMM + read-only cdf gather ----------------
// Per pair: 2 LDS gathers + 2 FMA into a register. No RMW histogram at all.
// Last-finished block (device-scope ticket) writes out[0].
__global__ __launch_bounds__(256, 2) void hl_neg(const ushort* __restrict__ nemb,
                                                 const int* __restrict__ cls,
                                                 const float* __restrict__ gPos,
                                                 float* __restrict__ gLoss,
                                                 float* __restrict__ gCnt,
                                                 unsigned int* __restrict__ gDone,
                                                 float* __restrict__ out) {
    // flat grid: blocks 0..495 = strictly-upper tile pairs, 496..527 = diagonal
    int ti, tj;
    {
        int t = blockIdx.x;
        if (t < NOFF) {
            ti = 0;
            int rem = t;
            while (rem >= GRID_T - 1 - ti) { rem -= GRID_T - 1 - ti; ++ti; }
            tj = ti + 1 + rem;
        } else {
            ti = tj = t - NOFF;
        }
    }

    __shared__ ushort As[PTILE * PLSTR];      // 34816 B
    __shared__ ushort Bs[PTILE * PLSTR];      // 34816 B
    __shared__ float cdfL[NREPC * 101];       // 6464 B
    __shared__ float scan[128];
    __shared__ float red[9];                  // 4 loss + 4 cnt + sp
    __shared__ int clsA[PTILE], clsB[PTILE];

    const int tid = threadIdx.x;
    if (tid < PTILE) clsA[tid] = cls[ti * PTILE + tid];
    else             clsB[tid - PTILE] = cls[tj * PTILE + (tid - PTILE)];

    // ---- cdf prologue: inclusive scan of gPos, 16 LDS replicas ----
    if (tid < 128) scan[tid] = (tid < NSTEPS) ? gPos[tid] : 0.f;
    __syncthreads();
    for (int off = 1; off < 128; off <<= 1) {
        float v = 0.f;
        if (tid < 128 && tid >= off) v = scan[tid - off];
        __syncthreads();
        if (tid < 128) scan[tid] += v;
        __syncthreads();
    }
    if (tid == 0) red[8] = scan[NSTEPS - 1];   // sp
    __syncthreads();
    const float invsp = 1.0f / red[8];
    for (int i = tid; i < NREPC * NSTEPS; i += 256) {
        int r = i / NSTEPS, b = i - r * NSTEPS;
        cdfL[r * 101 + b] = scan[b] * invsp;
    }

    // ---- stage tiles ----
    #pragma unroll
    for (int it = 0; it < 8; ++it) {
        int idx = it * 256 + tid;
        int row = idx >> 4;
        int cch = idx & 15;
        const float4 va = *(const float4*)(nemb + (size_t)(ti * PTILE + row) * DD + cch * 8);
        const float4 vb = *(const float4*)(nemb + (size_t)(tj * PTILE + row) * DD + cch * 8);
        *(float4*)(&As[row * PLSTR + cch * 8]) = va;
        *(float4*)(&Bs[row * PLSTR + cch * 8]) = vb;
    }
    __syncthreads();   // covers cdf replicas + cls + tiles

    const int lane = tid & 63;
    const int wid = tid >> 6;
    const int wr = wid >> 1, wc = wid & 1;
    const int lr = lane & 15;
    const int kg = lane >> 4;

    f32x4 zero4 = {0.f, 0.f, 0.f, 0.f};
    f32x4 acc[4][4];
    #pragma unroll
    for (int a = 0; a < 4; ++a)
        #pragma unroll
        for (int b = 0; b < 4; ++b) acc[a][b] = zero4;

    #pragma unroll
    for (int ks = 0; ks < 4; ++ks) {
        bf16x8 af[4], bfr[4];
        #pragma unroll
        for (int f = 0; f < 4; ++f) {
            int arow = wr * 64 + f * 16 + lr;
            af[f] = *(const bf16x8*)(&As[arow * PLSTR + ks * 32 + kg * 8]);
            int brow = wc * 64 + f * 16 + lr;
            bfr[f] = *(const bf16x8*)(&Bs[brow * PLSTR + ks * 32 + kg * 8]);
        }
        #pragma unroll
        for (int fa = 0; fa < 4; ++fa)
            #pragma unroll
            for (int fb = 0; fb < 4; ++fb)
                acc[fa][fb] = __builtin_amdgcn_mfma_f32_16x16x32_bf16(af[fa], bfr[fb], acc[fa][fb], 0, 0, 0);
    }

    // ---- gather epilogue: branch-free, read-only cdf lookups ----
    constexpr float STEPF = 2.0f / 99.0f;
    constexpr float INVSTEP = 49.5f;
    constexpr float CLIPV = 1.0f - 1e-6f;

    const int li_base = wr * 64 + (kg << 2);
    const int lj_base = wc * 64 + lr;
    const float* crep = &cdfL[(lane & 15) * 101];

    int ca[16];
    #pragma unroll
    for (int fa = 0; fa < 4; ++fa)
        #pragma unroll
        for (int j = 0; j < 4; ++j) ca[fa * 4 + j] = clsA[li_base + fa * 16 + j];

    const bool offdiag = (ti != tj);
    float lacc = 0.f, lcnt = 0.f;

    #pragma unroll
    for (int fb = 0; fb < 4; ++fb) {
        const int lj = lj_base + fb * 16;
        const int cb = clsB[lj];
        #pragma unroll
        for (int fa = 0; fa < 4; ++fa) {
            const int li0 = li_base + fa * 16;
            f32x4 v = acc[fa][fb];
            #pragma unroll
            for (int j = 0; j < 4; ++j) {
                const int li = li0 + j;
                const bool mneg = (offdiag || (li < lj)) && (ca[fa * 4 + j] != cb);
                float s = v[j];
                s = fminf(fmaxf(s, -CLIPV), CLIPV);
                float u = (s + CLIPV) * INVSTEP;
                int jb = (int)u;
                if (jb > 98) jb = 98;
                float t_j = (float)jb * STEPF - 1.0f;
                float w_hi = (s - t_j) * INVSTEP;
                float w_lo = 1.0f - w_hi;
                float c0 = crep[jb];
                float c1 = crep[jb + 1];
                float m = mneg ? 1.0f : 0.0f;
                lacc = fmaf(m, fmaf(w_lo, c0, w_hi * c1), lacc);
                lcnt += m;
            }
        }
    }

    // ---- reduce: wave shuffle -> 4 partials -> 2 atomics into 32 slots ----
    #pragma unroll
    for (int off = 32; off > 0; off >>= 1) {
        lacc += __shfl_xor(lacc, off);
        lcnt += __shfl_xor(lcnt, off);
    }
    if (lane == 0) { red[wid] = lacc; red[4 + wid] = lcnt; }
    __syncthreads();
    if (tid == 0) {
        float L = red[0] + red[1] + red[2] + red[3];
        float C = red[4] + red[5] + red[6] + red[7];
        faddf(&gLoss[blockIdx.x & 31], L);
        faddf(&gCnt[blockIdx.x & 31], C);
        __threadfence();
        unsigned int tk = atomicAdd(gDone, 1u);
        if (tk == NBLK - 1) {          // last block finalizes
            __threadfence();
            float ls = 0.f, cs = 0.f;
            for (int i = 0; i < 32; ++i) {
                ls += __hip_atomic_load(&gLoss[i], __ATOMIC_RELAXED, __HIP_MEMORY_SCOPE_AGENT);
                cs += __hip_atomic_load(&gCnt[i], __ATOMIC_RELAXED, __HIP_MEMORY_SCOPE_AGENT);
            }
            // cdf already contains 1/sp -> loss = ls / sn
            out[0] = ls / cs;
        }
    }
}

extern "C" void kernel_launch(void* const* d_in, const int* in_sizes, int n_in,
                              void* d_out, int out_size, void* d_ws, size_t ws_size,
                              hipStream_t stream) {
    const float* emb = (const float*)d_in[0];
    const int* classes = (const int*)d_in[1];
    float* out = (float*)d_out;

    ushort* nemb = (ushort*)d_ws;                                   // 1 MB
    float* gPos = (float*)((char*)d_ws + (size_t)BN * DD * sizeof(ushort));
    float* gLoss = gPos + NSTEPS;           // 32 slots
    float* gCnt = gLoss + 32;               // 32 slots
    unsigned int* gDone = (unsigned int*)(gCnt + 32);

    hipMemsetAsync(gPos, 0, (NSTEPS + 64 + 1) * sizeof(float), stream);

    hl_normalize<<<BN / 4, 256, 0, stream>>>(emb, nemb);
    hl_poscls<<<NSTEPS, 256, 0, stream>>>(nemb, classes, gPos);
    hl_neg<<<NBLK, 256, 0, stream>>>(nemb, classes, gPos, gLoss, gCnt, gDone, out);
}

// Round 23
// 47.027 us; speedup vs baseline: 2.6185x; 1.6333x over previous
//
#include <hip/hip_runtime.h>
#include <hip/hip_bf16.h>
#include <cstddef>

#define BN 4096
#define DD 128
#define NSTEPS 100
#define PTILE 128
#define PLSTR 136   // bf16 elems per LDS row: 128 + 8 pad -> 272 B stride
#define GRID_T (BN / PTILE)   // 32
#define NOFF 496    // strictly-upper tile pairs (ti<tj)
#define NBLK 528    // + 32 diagonal tiles
#define NREPC 16    // replicas, stride 101 (101%32=5 -> spread banks)

typedef __attribute__((ext_vector_type(8))) short bf16x8;
typedef __attribute__((ext_vector_type(4))) float f32x4;

__device__ __forceinline__ void faddf(float* p, float v) { unsafeAtomicAdd(p, v); }

// ---------------- normalize + convert to bf16: one wave per row ----------------
__global__ __launch_bounds__(256) void hl_normalize(const float* __restrict__ emb,
                                                    ushort* __restrict__ out) {
    int w = threadIdx.x >> 6;
    int lane = threadIdx.x & 63;
    int row = (blockIdx.x << 2) + w;
    const float2 v = *(const float2*)(emb + (size_t)row * DD + 2 * lane);
    float ss = v.x * v.x + v.y * v.y;
    #pragma unroll
    for (int off = 32; off > 0; off >>= 1) ss += __shfl_xor(ss, off);
    float inv = 1.0f / sqrtf(ss);
    __hip_bfloat16 b0 = __float2bfloat16(v.x * inv);
    __hip_bfloat16 b1 = __float2bfloat16(v.y * inv);
    ushort2 pk;
    pk.x = *(ushort*)&b0;
    pk.y = *(ushort*)&b1;
    *(ushort2*)(out + (size_t)row * DD + 2 * lane) = pk;
}

// ---------------- POS histogram: per-class MFMA gram matrix ----------------
// r20 post-mortem: scalar-dot version serialized its loads (VGPR=12) -> 41us.
// Now: compact members, stage 64-row sub-tiles into LDS, MFMA 64x64 gram
// (4 waves x 16 mfma_16x16x32), masked epilogue -> 16-replica atomic hist.
__global__ __launch_bounds__(256) void hl_poscls(const ushort* __restrict__ nemb,
                                                 const int* __restrict__ cls,
                                                 float* __restrict__ gPos) {
    const int c = blockIdx.x;           // one block per class
    __shared__ int idx[256];
    __shared__ int scan[256];
    __shared__ ushort As[64 * PLSTR];   // 17408 B
    __shared__ ushort Bs[64 * PLSTR];   // 17408 B
    __shared__ float hpos[NREPC * 101]; // 6464 B
    __shared__ int mTot;
    const int tid = threadIdx.x;

    for (int i = tid; i < NREPC * 101; i += 256) hpos[i] = 0.f;

    // deterministic compaction: thread t owns elements [16t, 16t+16)
    const int base = tid * 16;
    int myCnt = 0;
    #pragma unroll
    for (int k = 0; k < 16; ++k) myCnt += (cls[base + k] == c);
    scan[tid] = myCnt;
    __syncthreads();
    for (int s = 1; s < 256; s <<= 1) {
        int v = (tid >= s) ? scan[tid - s] : 0;
        __syncthreads();
        scan[tid] += v;
        __syncthreads();
    }
    int w = scan[tid] - myCnt;          // exclusive offset
    if (tid == 255) mTot = scan[255] > 256 ? 256 : scan[255];
    #pragma unroll
    for (int k = 0; k < 16; ++k) {
        if (cls[base + k] == c && w < 256) { idx[w] = base + k; ++w; }
    }
    __syncthreads();
    const int m = mTot;
    const int nt = (m + 63) >> 6;       // 64-row sub-tiles (m~41 -> 1)

    constexpr float STEPF = 2.0f / 99.0f;
    constexpr float INVSTEP = 49.5f;
    constexpr float CLIPV = 1.0f - 1e-6f;

    const int lane = tid & 63;
    const int wv = tid >> 6;            // wave 0..3: A-rows wv*16..wv*16+15
    const int lr = lane & 15;
    const int kg = lane >> 4;
    const int rep = (lane & 15) * 101;

    for (int si = 0; si < nt; ++si) {
        for (int sj = si; sj < nt; ++sj) {
            __syncthreads();            // prior epilogue / hist-zero done
            // stage 64 rows x 16 chunks(16B) per tile; pad with idx[0] dup
            #pragma unroll
            for (int it = 0; it < 4; ++it) {
                int q = it * 256 + tid;   // 0..1023
                int row = q >> 4;
                int ch = q & 15;
                int ga = si * 64 + row;
                int gb = sj * 64 + row;
                int ra = idx[ga < m ? ga : 0];
                int rb = idx[gb < m ? gb : 0];
                *(float4*)(&As[row * PLSTR + ch * 8]) =
                    *(const float4*)(nemb + (size_t)ra * DD + ch * 8);
                *(float4*)(&Bs[row * PLSTR + ch * 8]) =
                    *(const float4*)(nemb + (size_t)rb * DD + ch * 8);
            }
            __syncthreads();

            f32x4 zero4 = {0.f, 0.f, 0.f, 0.f};
            f32x4 pacc[4] = {zero4, zero4, zero4, zero4};
            #pragma unroll
            for (int ks = 0; ks < 4; ++ks) {
                bf16x8 af = *(const bf16x8*)(&As[(wv * 16 + lr) * PLSTR + ks * 32 + kg * 8]);
                #pragma unroll
                for (int fb = 0; fb < 4; ++fb) {
                    bf16x8 bf = *(const bf16x8*)(&Bs[(fb * 16 + lr) * PLSTR + ks * 32 + kg * 8]);
                    pacc[fb] = __builtin_amdgcn_mfma_f32_16x16x32_bf16(af, bf, pacc[fb], 0, 0, 0);
                }
            }

            // epilogue: D row = wv*16+kg*4+j (A member), col = fb*16+lr (B member)
            #pragma unroll
            for (int fb = 0; fb < 4; ++fb) {
                const int gb = sj * 64 + fb * 16 + lr;
                #pragma unroll
                for (int j = 0; j < 4; ++j) {
                    const int ga = si * 64 + wv * 16 + kg * 4 + j;
                    if (ga < gb && gb < m) {
                        float s = pacc[fb][j];
                        s = fminf(fmaxf(s, -CLIPV), CLIPV);
                        float u = (s + CLIPV) * INVSTEP;
                        int jb = (int)u;
                        if (jb > 98) jb = 98;
                        float t_j = (float)jb * STEPF - 1.0f;
                        float w_hi = (s - t_j) * INVSTEP;
                        float w_lo = 1.0f - w_hi;
                        faddf(&hpos[rep + jb], w_lo);
                        faddf(&hpos[rep + jb + 1], w_hi);
                    }
                }
            }
        }
    }
    __syncthreads();
    if (tid < NSTEPS) {
        float v = 0.f;
        #pragma unroll
        for (int r = 0; r < NREPC; ++r) v += hpos[r * 101 + tid];
        if (v != 0.f) faddf(&gPos[tid], v);
    }
}

// ---------------- NEG pass: MFMA GEMM + read-only cdf gather ----------------
// Per pair: 2 LDS gathers + 2 FMA into a register. No RMW histogram at all.
// Last-finished block (device-scope ticket) writes out[0].
__global__ __launch_bounds__(256, 2) void hl_neg(const ushort* __restrict__ nemb,
                                                 const int* __restrict__ cls,
                                                 const float* __restrict__ gPos,
                                                 float* __restrict__ gLoss,
                                                 float* __restrict__ gCnt,
                                                 unsigned int* __restrict__ gDone,
                                                 float* __restrict__ out) {
    // flat grid: blocks 0..495 = strictly-upper tile pairs, 496..527 = diagonal
    int ti, tj;
    {
        int t = blockIdx.x;
        if (t < NOFF) {
            ti = 0;
            int rem = t;
            while (rem >= GRID_T - 1 - ti) { rem -= GRID_T - 1 - ti; ++ti; }
            tj = ti + 1 + rem;
        } else {
            ti = tj = t - NOFF;
        }
    }

    __shared__ ushort As[PTILE * PLSTR];      // 34816 B
    __shared__ ushort Bs[PTILE * PLSTR];      // 34816 B
    __shared__ float cdfL[NREPC * 101];       // 6464 B
    __shared__ float scan[128];
    __shared__ float red[9];                  // 4 loss + 4 cnt + sp
    __shared__ int clsA[PTILE], clsB[PTILE];

    const int tid = threadIdx.x;
    if (tid < PTILE) clsA[tid] = cls[ti * PTILE + tid];
    else             clsB[tid - PTILE] = cls[tj * PTILE + (tid - PTILE)];

    // ---- cdf prologue: inclusive scan of gPos, 16 LDS replicas ----
    if (tid < 128) scan[tid] = (tid < NSTEPS) ? gPos[tid] : 0.f;
    __syncthreads();
    for (int off = 1; off < 128; off <<= 1) {
        float v = 0.f;
        if (tid < 128 && tid >= off) v = scan[tid - off];
        __syncthreads();
        if (tid < 128) scan[tid] += v;
        __syncthreads();
    }
    if (tid == 0) red[8] = scan[NSTEPS - 1];   // sp
    __syncthreads();
    const float invsp = 1.0f / red[8];
    for (int i = tid; i < NREPC * NSTEPS; i += 256) {
        int r = i / NSTEPS, b = i - r * NSTEPS;
        cdfL[r * 101 + b] = scan[b] * invsp;
    }

    // ---- stage tiles ----
    #pragma unroll
    for (int it = 0; it < 8; ++it) {
        int idx = it * 256 + tid;
        int row = idx >> 4;
        int cch = idx & 15;
        const float4 va = *(const float4*)(nemb + (size_t)(ti * PTILE + row) * DD + cch * 8);
        const float4 vb = *(const float4*)(nemb + (size_t)(tj * PTILE + row) * DD + cch * 8);
        *(float4*)(&As[row * PLSTR + cch * 8]) = va;
        *(float4*)(&Bs[row * PLSTR + cch * 8]) = vb;
    }
    __syncthreads();   // covers cdf replicas + cls + tiles

    const int lane = tid & 63;
    const int wid = tid >> 6;
    const int wr = wid >> 1, wc = wid & 1;
    const int lr = lane & 15;
    const int kg = lane >> 4;

    f32x4 zero4 = {0.f, 0.f, 0.f, 0.f};
    f32x4 acc[4][4];
    #pragma unroll
    for (int a = 0; a < 4; ++a)
        #pragma unroll
        for (int b = 0; b < 4; ++b) acc[a][b] = zero4;

    #pragma unroll
    for (int ks = 0; ks < 4; ++ks) {
        bf16x8 af[4], bfr[4];
        #pragma unroll
        for (int f = 0; f < 4; ++f) {
            int arow = wr * 64 + f * 16 + lr;
            af[f] = *(const bf16x8*)(&As[arow * PLSTR + ks * 32 + kg * 8]);
            int brow = wc * 64 + f * 16 + lr;
            bfr[f] = *(const bf16x8*)(&Bs[brow * PLSTR + ks * 32 + kg * 8]);
        }
        #pragma unroll
        for (int fa = 0; fa < 4; ++fa)
            #pragma unroll
            for (int fb = 0; fb < 4; ++fb)
                acc[fa][fb] = __builtin_amdgcn_mfma_f32_16x16x32_bf16(af[fa], bfr[fb], acc[fa][fb], 0, 0, 0);
    }

    // ---- gather epilogue: branch-free, read-only cdf lookups ----
    constexpr float STEPF = 2.0f / 99.0f;
    constexpr float INVSTEP = 49.5f;
    constexpr float CLIPV = 1.0f - 1e-6f;

    const int li_base = wr * 64 + (kg << 2);
    const int lj_base = wc * 64 + lr;
    const float* crep = &cdfL[(lane & 15) * 101];

    int ca[16];
    #pragma unroll
    for (int fa = 0; fa < 4; ++fa)
        #pragma unroll
        for (int j = 0; j < 4; ++j) ca[fa * 4 + j] = clsA[li_base + fa * 16 + j];

    const bool offdiag = (ti != tj);
    float lacc = 0.f, lcnt = 0.f;

    #pragma unroll
    for (int fb = 0; fb < 4; ++fb) {
        const int lj = lj_base + fb * 16;
        const int cb = clsB[lj];
        #pragma unroll
        for (int fa = 0; fa < 4; ++fa) {
            const int li0 = li_base + fa * 16;
            f32x4 v = acc[fa][fb];
            #pragma unroll
            for (int j = 0; j < 4; ++j) {
                const int li = li0 + j;
                const bool mneg = (offdiag || (li < lj)) && (ca[fa * 4 + j] != cb);
                float s = v[j];
                s = fminf(fmaxf(s, -CLIPV), CLIPV);
                float u = (s + CLIPV) * INVSTEP;
                int jb = (int)u;
                if (jb > 98) jb = 98;
                float t_j = (float)jb * STEPF - 1.0f;
                float w_hi = (s - t_j) * INVSTEP;
                float w_lo = 1.0f - w_hi;
                float c0 = crep[jb];
                float c1 = crep[jb + 1];
                float m = mneg ? 1.0f : 0.0f;
                lacc = fmaf(m, fmaf(w_lo, c0, w_hi * c1), lacc);
                lcnt += m;
            }
        }
    }

    // ---- reduce: wave shuffle -> 4 partials -> 2 atomics into 32 slots ----
    #pragma unroll
    for (int off = 32; off > 0; off >>= 1) {
        lacc += __shfl_xor(lacc, off);
        lcnt += __shfl_xor(lcnt, off);
    }
    if (lane == 0) { red[wid] = lacc; red[4 + wid] = lcnt; }
    __syncthreads();
    if (tid == 0) {
        float L = red[0] + red[1] + red[2] + red[3];
        float C = red[4] + red[5] + red[6] + red[7];
        faddf(&gLoss[blockIdx.x & 31], L);
        faddf(&gCnt[blockIdx.x & 31], C);
        __threadfence();
        unsigned int tk = atomicAdd(gDone, 1u);
        if (tk == NBLK - 1) {          // last block finalizes
            __threadfence();
            float ls = 0.f, cs = 0.f;
            for (int i = 0; i < 32; ++i) {
                ls += __hip_atomic_load(&gLoss[i], __ATOMIC_RELAXED, __HIP_MEMORY_SCOPE_AGENT);
                cs += __hip_atomic_load(&gCnt[i], __ATOMIC_RELAXED, __HIP_MEMORY_SCOPE_AGENT);
            }
            // cdf already contains 1/sp -> loss = ls / sn
            out[0] = ls / cs;
        }
    }
}

extern "C" void kernel_launch(void* const* d_in, const int* in_sizes, int n_in,
                              void* d_out, int out_size, void* d_ws, size_t ws_size,
                              hipStream_t stream) {
    const float* emb = (const float*)d_in[0];
    const int* classes = (const int*)d_in[1];
    float* out = (float*)d_out;

    ushort* nemb = (ushort*)d_ws;                                   // 1 MB
    float* gPos = (float*)((char*)d_ws + (size_t)BN * DD * sizeof(ushort));
    float* gLoss = gPos + NSTEPS;           // 32 slots
    float* gCnt = gLoss + 32;               // 32 slots
    unsigned int* gDone = (unsigned int*)(gCnt + 32);

    hipMemsetAsync(gPos, 0, (NSTEPS + 64 + 1) * sizeof(float), stream);

    hl_normalize<<<BN / 4, 256, 0, stream>>>(emb, nemb);
    hl_poscls<<<NSTEPS, 256, 0, stream>>>(nemb, classes, gPos);
    hl_neg<<<NBLK, 256, 0, stream>>>(nemb, classes, gPos, gLoss, gCnt, gDone, out);
}

// Round 25
// 46.342 us; speedup vs baseline: 2.6571x; 1.0148x over previous
//
#include <hip/hip_runtime.h>
#include <hip/hip_bf16.h>
#include <cstddef>

#define BN 4096
#define DD 128
#define NSTEPS 100
#define PTILE 128
#define PLSTR 136   // poscls LDS row stride (padded; poscls keeps float4 staging)
#define GRID_T (BN / PTILE)   // 32
#define NOFF 496    // strictly-upper tile pairs (ti<tj)
#define NBLK2 512   // 496 off-diag + 16 blocks x 2 diagonal tiles
#define NREPC 16    // replicas, stride 101 (101%32=5 -> spread banks)

typedef __attribute__((ext_vector_type(8))) short bf16x8;
typedef __attribute__((ext_vector_type(4))) float f32x4;

__device__ __forceinline__ void faddf(float* p, float v) { unsafeAtomicAdd(p, v); }

// ws control block (after nemb): gPos[100] gLoss[32] gCnt[32] gDone gDoneP | gCdf[100]
#define ZERON 166

// ---------------- normalize + convert to bf16 + zero control block ----------------
__global__ __launch_bounds__(256) void hl_normalize(const float* __restrict__ emb,
                                                    ushort* __restrict__ out,
                                                    float* __restrict__ zero_blk) {
    if (blockIdx.x == 0 && threadIdx.x < ZERON) zero_blk[threadIdx.x] = 0.f;
    int w = threadIdx.x >> 6;
    int lane = threadIdx.x & 63;
    int row = (blockIdx.x << 2) + w;
    const float2 v = *(const float2*)(emb + (size_t)row * DD + 2 * lane);
    float ss = v.x * v.x + v.y * v.y;
    #pragma unroll
    for (int off = 32; off > 0; off >>= 1) ss += __shfl_xor(ss, off);
    float inv = 1.0f / sqrtf(ss);
    __hip_bfloat16 b0 = __float2bfloat16(v.x * inv);
    __hip_bfloat16 b1 = __float2bfloat16(v.y * inv);
    ushort2 pk;
    pk.x = *(ushort*)&b0;
    pk.y = *(ushort*)&b1;
    *(ushort2*)(out + (size_t)row * DD + 2 * lane) = pk;
}

// ---------------- POS histogram: per-class MFMA gram; last block builds cdf ----------
__global__ __launch_bounds__(256) void hl_poscls(const ushort* __restrict__ nemb,
                                                 const int* __restrict__ cls,
                                                 float* __restrict__ gPos,
                                                 unsigned int* __restrict__ gDoneP,
                                                 float* __restrict__ gCdf) {
    const int c = blockIdx.x;           // one block per class
    __shared__ int idx[256];
    __shared__ int scan[256];
    __shared__ ushort As[64 * PLSTR];   // 17408 B
    __shared__ ushort Bs[64 * PLSTR];   // 17408 B
    __shared__ float hpos[NREPC * 101]; // 6464 B
    __shared__ int mTot;
    __shared__ int lastFlag;
    const int tid = threadIdx.x;

    for (int i = tid; i < NREPC * 101; i += 256) hpos[i] = 0.f;

    // deterministic compaction: thread t owns elements [16t, 16t+16)
    const int base = tid * 16;
    int myCnt = 0;
    #pragma unroll
    for (int k = 0; k < 16; ++k) myCnt += (cls[base + k] == c);
    scan[tid] = myCnt;
    __syncthreads();
    for (int s = 1; s < 256; s <<= 1) {
        int v = (tid >= s) ? scan[tid - s] : 0;
        __syncthreads();
        scan[tid] += v;
        __syncthreads();
    }
    int w = scan[tid] - myCnt;          // exclusive offset
    if (tid == 255) mTot = scan[255] > 256 ? 256 : scan[255];
    #pragma unroll
    for (int k = 0; k < 16; ++k) {
        if (cls[base + k] == c && w < 256) { idx[w] = base + k; ++w; }
    }
    __syncthreads();
    const int m = mTot;
    const int nt = (m + 63) >> 6;       // 64-row sub-tiles (m~41 -> 1)

    constexpr float STEPF = 2.0f / 99.0f;
    constexpr float INVSTEP = 49.5f;
    constexpr float CLIPV = 1.0f - 1e-6f;

    const int lane = tid & 63;
    const int wv = tid >> 6;            // wave 0..3: A-rows wv*16..wv*16+15
    const int lr = lane & 15;
    const int kg = lane >> 4;
    const int rep = (lane & 15) * 101;

    for (int si = 0; si < nt; ++si) {
        for (int sj = si; sj < nt; ++sj) {
            __syncthreads();
            #pragma unroll
            for (int it = 0; it < 4; ++it) {
                int q = it * 256 + tid;   // 0..1023
                int row = q >> 4;
                int ch = q & 15;
                int ga = si * 64 + row;
                int gb = sj * 64 + row;
                int ra = idx[ga < m ? ga : 0];
                int rb = idx[gb < m ? gb : 0];
                *(float4*)(&As[row * PLSTR + ch * 8]) =
                    *(const float4*)(nemb + (size_t)ra * DD + ch * 8);
                *(float4*)(&Bs[row * PLSTR + ch * 8]) =
                    *(const float4*)(nemb + (size_t)rb * DD + ch * 8);
            }
            __syncthreads();

            f32x4 zero4 = {0.f, 0.f, 0.f, 0.f};
            f32x4 pacc[4] = {zero4, zero4, zero4, zero4};
            #pragma unroll
            for (int ks = 0; ks < 4; ++ks) {
                bf16x8 af = *(const bf16x8*)(&As[(wv * 16 + lr) * PLSTR + ks * 32 + kg * 8]);
                #pragma unroll
                for (int fb = 0; fb < 4; ++fb) {
                    bf16x8 bf = *(const bf16x8*)(&Bs[(fb * 16 + lr) * PLSTR + ks * 32 + kg * 8]);
                    pacc[fb] = __builtin_amdgcn_mfma_f32_16x16x32_bf16(af, bf, pacc[fb], 0, 0, 0);
                }
            }

            #pragma unroll
            for (int fb = 0; fb < 4; ++fb) {
                const int gb = sj * 64 + fb * 16 + lr;
                #pragma unroll
                for (int j = 0; j < 4; ++j) {
                    const int ga = si * 64 + wv * 16 + kg * 4 + j;
                    if (ga < gb && gb < m) {
                        float s = pacc[fb][j];
                        s = fminf(fmaxf(s, -CLIPV), CLIPV);
                        float u = (s + CLIPV) * INVSTEP;
                        int jb = (int)u;
                        if (jb > 98) jb = 98;
                        float t_j = (float)jb * STEPF - 1.0f;
                        float w_hi = (s - t_j) * INVSTEP;
                        float w_lo = 1.0f - w_hi;
                        faddf(&hpos[rep + jb], w_lo);
                        faddf(&hpos[rep + jb + 1], w_hi);
                    }
                }
            }
        }
    }
    __syncthreads();
    if (tid < NSTEPS) {
        float v = 0.f;
        #pragma unroll
        for (int r = 0; r < NREPC; ++r) v += hpos[r * 101 + tid];
        if (v != 0.f) faddf(&gPos[tid], v);
    }
    __threadfence();
    if (tid == 0) {
        unsigned int tk = atomicAdd(gDoneP, 1u);
        lastFlag = (tk == NSTEPS - 1);
    }
    __syncthreads();
    if (lastFlag) {
        // build normalized cdf once (was: 14-barrier scan in every hl_neg block)
        float v = (tid < NSTEPS)
            ? __hip_atomic_load(&gPos[tid], __ATOMIC_RELAXED, __HIP_MEMORY_SCOPE_AGENT) : 0.f;
        if (tid < 128) hpos[tid] = v;
        __syncthreads();
        for (int off = 1; off < 128; off <<= 1) {
            float x = 0.f;
            if (tid < 128 && tid >= off) x = hpos[tid - off];
            __syncthreads();
            if (tid < 128) hpos[tid] += x;
            __syncthreads();
        }
        const float invsp = 1.0f / hpos[NSTEPS - 1];
        if (tid < NSTEPS) gCdf[tid] = hpos[tid] * invsp;
    }
}

// ---------------- NEG pass: gload_lds-staged MFMA GEMM + cdf gather ----------------
__global__ __launch_bounds__(256, 2) void hl_neg(const ushort* __restrict__ nemb,
                                                 const int* __restrict__ cls,
                                                 const float* __restrict__ gCdf,
                                                 float* __restrict__ gLoss,
                                                 float* __restrict__ gCnt,
                                                 unsigned int* __restrict__ gDone,
                                                 float* __restrict__ out) {
    __shared__ ushort As[PTILE * 128];        // 32768 B, unpadded (gload_lds dest)
    __shared__ ushort Bs[PTILE * 128];        // 32768 B
    __shared__ float cdfL[NREPC * 101];       // 6464 B
    __shared__ float red[8];
    __shared__ int clsA[PTILE], clsB[PTILE];

    const int tid = threadIdx.x;
    const int lane = tid & 63;
    const int wid = tid >> 6;
    const int wr = wid >> 1, wc = wid & 1;
    const int lr = lane & 15;
    const int kg = lane >> 4;

    // unit decode: b<496 off-diag; else 2 diagonal tiles per block
    int ti0, tj0, ti1 = 0, nu = 1;
    {
        int t = blockIdx.x;
        if (t < NOFF) {
            int ti = 0, rem = t;
            while (rem >= GRID_T - 1 - ti) { rem -= GRID_T - 1 - ti; ++ti; }
            ti0 = ti; tj0 = ti + 1 + rem;
        } else {
            int d = (t - NOFF) * 2;
            ti0 = tj0 = d; ti1 = d + 1; nu = 2;
        }
    }

    // cdf replicas (precomputed by hl_poscls last block; kernel-boundary coherent)
    for (int i = tid; i < NREPC * NSTEPS; i += 256) {
        int r = i / NSTEPS, b = i - r * NSTEPS;
        cdfL[r * 101 + b] = gCdf[b];
    }

    constexpr float STEPF = 2.0f / 99.0f;
    constexpr float INVSTEP = 49.5f;
    constexpr float CLIPV = 1.0f - 1e-6f;
    const float* crep = &cdfL[(lane & 15) * 101];
    const int li_base = wr * 64 + (kg << 2);
    const int lj_base = wc * 64 + lr;

    float lacc = 0.f, lcnt = 0.f;
    const int rloc = lane >> 4;          // staging: row within 4-row group
    const int pch = lane & 15;           // staging: physical 16B chunk

    for (int u = 0; u < nu; ++u) {
        const int ti = u ? ti1 : ti0;
        const int tj = u ? ti1 : tj0;    // u==1 only for diag pairs (ti1==tj1)
        const bool diag = (ti == tj);

        __syncthreads();                 // prior unit's LDS reads complete
        if (tid < PTILE) clsA[tid] = cls[ti * PTILE + tid];
        else             clsB[tid - PTILE] = cls[tj * PTILE + (tid - PTILE)];

        // stage via global_load_lds(16B): wave wv covers rows [wv*32, wv*32+32),
        // linear LDS dest; XOR-swizzle applied on the per-lane GLOBAL source
        // (phys_chunk = logical ^ (row&7)) so reads can de-conflict (rule 21).
        {
            const ushort* Ag = nemb + (size_t)(ti * PTILE) * DD;
            const ushort* Bg = nemb + (size_t)(tj * PTILE) * DD;
            #pragma unroll
            for (int t = 0; t < 8; ++t) {
                int row = wid * 32 + t * 4 + rloc;
                int lch = pch ^ (row & 7);
                const ushort* ga = Ag + (size_t)row * DD + lch * 8;
                ushort* la = &As[(wid * 32 + t * 4) * 128];
                __builtin_amdgcn_global_load_lds(
                    (const __attribute__((address_space(1))) void*)ga,
                    (__attribute__((address_space(3))) void*)la, 16, 0, 0);
            }
            if (!diag) {
                #pragma unroll
                for (int t = 0; t < 8; ++t) {
                    int row = wid * 32 + t * 4 + rloc;
                    int lch = pch ^ (row & 7);
                    const ushort* gb = Bg + (size_t)row * DD + lch * 8;
                    ushort* lb = &Bs[(wid * 32 + t * 4) * 128];
                    __builtin_amdgcn_global_load_lds(
                        (const __attribute__((address_space(1))) void*)gb,
                        (__attribute__((address_space(3))) void*)lb, 16, 0, 0);
                }
            }
        }
        __syncthreads();                 // vmcnt(0) drained by compiler before barrier

        const ushort* Bsel = diag ? As : Bs;
        const int* clsBsel = diag ? clsA : clsB;

        f32x4 zero4 = {0.f, 0.f, 0.f, 0.f};
        f32x4 acc[4][4];
        #pragma unroll
        for (int a = 0; a < 4; ++a)
            #pragma unroll
            for (int b = 0; b < 4; ++b) acc[a][b] = zero4;

        #pragma unroll
        for (int ks = 0; ks < 4; ++ks) {
            bf16x8 af[4], bfr[4];
            #pragma unroll
            for (int f = 0; f < 4; ++f) {
                int arow = wr * 64 + f * 16 + lr;
                int pca = ((ks << 2) | kg) ^ (arow & 7);
                af[f] = *(const bf16x8*)(&As[arow * 128 + pca * 8]);
                int brow = wc * 64 + f * 16 + lr;
                int pcb = ((ks << 2) | kg) ^ (brow & 7);
                bfr[f] = *(const bf16x8*)(&Bsel[brow * 128 + pcb * 8]);
            }
            #pragma unroll
            for (int fa = 0; fa < 4; ++fa)
                #pragma unroll
                for (int fb = 0; fb < 4; ++fb)
                    acc[fa][fb] = __builtin_amdgcn_mfma_f32_16x16x32_bf16(af[fa], bfr[fb], acc[fa][fb], 0, 0, 0);
        }

        int ca[16];
        #pragma unroll
        for (int fa = 0; fa < 4; ++fa)
            #pragma unroll
            for (int j = 0; j < 4; ++j) ca[fa * 4 + j] = clsA[li_base + fa * 16 + j];

        const bool offdiag = !diag;
        #pragma unroll
        for (int fb = 0; fb < 4; ++fb) {
            const int lj = lj_base + fb * 16;
            const int cb = clsBsel[lj];
            #pragma unroll
            for (int fa = 0; fa < 4; ++fa) {
                const int li0 = li_base + fa * 16;
                f32x4 v = acc[fa][fb];
                #pragma unroll
                for (int j = 0; j < 4; ++j) {
                    const int li = li0 + j;
                    const bool mneg = (offdiag || (li < lj)) && (ca[fa * 4 + j] != cb);
                    float s = v[j];
                    s = fminf(fmaxf(s, -CLIPV), CLIPV);
                    float uu = (s + CLIPV) * INVSTEP;
                    int jb = (int)uu;
                    if (jb > 98) jb = 98;
                    float t_j = (float)jb * STEPF - 1.0f;
                    float w_hi = (s - t_j) * INVSTEP;
                    float w_lo = 1.0f - w_hi;
                    float c0 = crep[jb];
                    float c1 = crep[jb + 1];
                    float mm = mneg ? 1.0f : 0.0f;
                    lacc = fmaf(mm, fmaf(w_lo, c0, w_hi * c1), lacc);
                    lcnt += mm;
                }
            }
        }
    }

    // reduce: wave shuffle -> 4 partials -> 2 atomics into 32 slots
    #pragma unroll
    for (int off = 32; off > 0; off >>= 1) {
        lacc += __shfl_xor(lacc, off);
        lcnt += __shfl_xor(lcnt, off);
    }
    if (lane == 0) { red[wid] = lacc; red[4 + wid] = lcnt; }
    __syncthreads();
    if (tid == 0) {
        float L = red[0] + red[1] + red[2] + red[3];
        float C = red[4] + red[5] + red[6] + red[7];
        faddf(&gLoss[blockIdx.x & 31], L);
        faddf(&gCnt[blockIdx.x & 31], C);
        __threadfence();
        unsigned int tk = atomicAdd(gDone, 1u);
        if (tk == NBLK2 - 1) {
            __threadfence();
            float ls = 0.f, cs = 0.f;
            for (int i = 0; i < 32; ++i) {
                ls += __hip_atomic_load(&gLoss[i], __ATOMIC_RELAXED, __HIP_MEMORY_SCOPE_AGENT);
                cs += __hip_atomic_load(&gCnt[i], __ATOMIC_RELAXED, __HIP_MEMORY_SCOPE_AGENT);
            }
            out[0] = ls / cs;            // cdf already contains 1/sp
        }
    }
}

extern "C" void kernel_launch(void* const* d_in, const int* in_sizes, int n_in,
                              void* d_out, int out_size, void* d_ws, size_t ws_size,
                              hipStream_t stream) {
    const float* emb = (const float*)d_in[0];
    const int* classes = (const int*)d_in[1];
    float* out = (float*)d_out;

    ushort* nemb = (ushort*)d_ws;                                   // 1 MB
    float* ctl = (float*)((char*)d_ws + (size_t)BN * DD * sizeof(ushort));
    float* gPos = ctl;                                // 100
    float* gLoss = gPos + NSTEPS;                     // 32
    float* gCnt = gLoss + 32;                         // 32
    unsigned int* gDone = (unsigned int*)(gCnt + 32); // 1
    unsigned int* gDoneP = gDone + 1;                 // 1
    float* gCdf = (float*)(gDoneP + 1);               // 100 (not zeroed; fully written)

    hl_normalize<<<BN / 4, 256, 0, stream>>>(emb, nemb, ctl);
    hl_poscls<<<NSTEPS, 256, 0, stream>>>(nemb, classes, gPos, gDoneP, gCdf);
    hl_neg<<<NBLK2, 256, 0, stream>>>(nemb, classes, gCdf, gLoss, gCnt, gDone, out);
}